// Round 15
// baseline (368.516 us; speedup 1.0000x reference)
//
#include <hip/hip_runtime.h>

#define NN 50000
#define EE 800000
#define NTILES (EE / 128)       // 6250 tiles of 128 edges (4 waves x 32)
#define NB ((NN + 1023) / 1024) // 49

typedef __attribute__((ext_vector_type(8))) short short8;
typedef __attribute__((ext_vector_type(16))) float f32x16;

static __device__ __forceinline__ unsigned short f2bf(float f) {
    unsigned u = __float_as_uint(f);
    u += 0x7fffu + ((u >> 16) & 1u);
    return (unsigned short)(u >> 16);
}
// packed f32x2 -> bf16x2 (single HW instruction, RTNE)
static __device__ __forceinline__ unsigned cvt_pk(float lo, float hi) {
    unsigned r;
    asm("v_cvt_pk_bf16_f32 %0, %1, %2" : "=v"(r) : "v"(lo), "v"(hi));
    return r;
}
static __device__ __forceinline__ float bf2f(unsigned short s) {
    return __uint_as_float((unsigned)s << 16);
}
static __device__ __forceinline__ f32x16 splat16(float v) {
    f32x16 r;
    #pragma unroll
    for (int i = 0; i < 16; ++i) r[i] = v;
    return r;
}

union U8 { short8 v; uint2 u[2]; };

// read an 8-bf16 MFMA fragment: elems [0..3] at k0, [4..7] at k0+8
static __device__ __forceinline__ short8 ldsfrag(const unsigned short* rowbase, int k0) {
    U8 t;
    t.u[0] = *(const uint2*)(rowbase + k0);
    t.u[1] = *(const uint2*)(rowbase + k0 + 8);
    return t.v;
}

// ---------------------------------------------------------------------------
// Kernel 1: Qh/Kh/Vh via MFMA. Block = 256 thr = 4 waves x 32 rows.
// ---------------------------------------------------------------------------
__global__ __launch_bounds__(256) void qkv_mfma_kernel(
    const float* __restrict__ x,
    const float* __restrict__ WQ, const float* __restrict__ WK, const float* __restrict__ WV,
    float* __restrict__ Qh, float* __restrict__ Kh, float* __restrict__ Vh)
{
    __shared__ unsigned short s_wq[64][68];
    __shared__ unsigned short s_wk[64][68];
    __shared__ unsigned short s_wv[64][68];

    int tid = threadIdx.x;
    #pragma unroll
    for (int t = 0; t < 8; ++t) {
        int idx = (t * 256 + tid) * 2;
        int r = idx >> 6, c = idx & 63;
        float2 w = *(const float2*)(WQ + idx);
        *(unsigned*)&s_wq[r][c] = cvt_pk(w.x, w.y);
        w = *(const float2*)(WK + idx);
        *(unsigned*)&s_wk[r][c] = cvt_pk(w.x, w.y);
        w = *(const float2*)(WV + idx);
        *(unsigned*)&s_wv[r][c] = cvt_pk(w.x, w.y);
    }
    __syncthreads();

    int wid = tid >> 6, lane = tid & 63;
    int m0 = blockIdx.x * 128 + wid * 32;
    int lo5 = lane & 31, hi = lane >> 5;

    int rowi = m0 + lo5;
    const float* arow = x + (size_t)(rowi < NN ? rowi : NN - 1) * 64;
    short8 af[4];
    #pragma unroll
    for (int ks = 0; ks < 4; ++ks) {
        int k0 = ks * 16 + hi * 4;
        float4 a0 = *(const float4*)(arow + k0);
        float4 a1 = *(const float4*)(arow + k0 + 8);
        U8 t;
        t.u[0] = make_uint2(cvt_pk(a0.x, a0.y), cvt_pk(a0.z, a0.w));
        t.u[1] = make_uint2(cvt_pk(a1.x, a1.y), cvt_pk(a1.z, a1.w));
        af[ks] = t.v;
    }

    #pragma unroll
    for (int nt = 0; nt < 2; ++nt) {
        int n = nt * 32 + lo5;
        f32x16 cQ = splat16(0.f), cK = splat16(0.f), cV = splat16(0.f);
        #pragma unroll
        for (int ks = 0; ks < 4; ++ks) {
            int k0 = ks * 16 + hi * 4;
            cQ = __builtin_amdgcn_mfma_f32_32x32x16_bf16(af[ks], ldsfrag(s_wq[n], k0), cQ, 0, 0, 0);
            cK = __builtin_amdgcn_mfma_f32_32x32x16_bf16(af[ks], ldsfrag(s_wk[n], k0), cK, 0, 0, 0);
            cV = __builtin_amdgcn_mfma_f32_32x32x16_bf16(af[ks], ldsfrag(s_wv[n], k0), cV, 0, 0, 0);
        }
        #pragma unroll
        for (int r = 0; r < 16; ++r) {
            int m = (r & 3) + 8 * (r >> 2) + 4 * hi;
            int gm = m0 + m;
            if (gm < NN) {
                Qh[(size_t)gm * 64 + n] = cQ[r];
                Kh[(size_t)gm * 64 + n] = cK[r];
                Vh[(size_t)gm * 64 + n] = cV[r];
            }
        }
    }
}

// ---------------------------------------------------------------------------
// CSR build: histogram -> hierarchical scan -> scatter (combined int2 + inv)
// ---------------------------------------------------------------------------
__global__ __launch_bounds__(256) void hist_kernel(const int* __restrict__ eidx,
                                                   int* __restrict__ cnt)
{
    int e = blockIdx.x * blockDim.x + threadIdx.x;
    atomicAdd(&cnt[eidx[e]], 1);
}

__global__ __launch_bounds__(1024) void scan1_kernel(const int* __restrict__ cnt,
                                                     int* __restrict__ rowstart,
                                                     int* __restrict__ bsum)
{
    __shared__ int buf[1024];
    int tid = threadIdx.x;
    int i = blockIdx.x * 1024 + tid;
    int v = (i < NN) ? cnt[i] : 0;
    buf[tid] = v;
    __syncthreads();
    for (int off = 1; off < 1024; off <<= 1) {
        int t = (tid >= off) ? buf[tid - off] : 0;
        __syncthreads();
        buf[tid] += t;
        __syncthreads();
    }
    if (i < NN) rowstart[i] = buf[tid] - v;
    if (tid == 1023) bsum[blockIdx.x] = buf[1023];
}

__global__ __launch_bounds__(64) void scan2_kernel(const int* __restrict__ bsum,
                                                   int* __restrict__ boff,
                                                   int* __restrict__ rowstart)
{
    int lane = threadIdx.x;
    int v = (lane < NB) ? bsum[lane] : 0;
    int s = v;
    #pragma unroll
    for (int off = 1; off < 64; off <<= 1) {
        int t = __shfl_up(s, off, 64);
        if (lane >= off) s += t;
    }
    if (lane < NB) boff[lane] = s - v;
    if (lane == 63) rowstart[NN] = s;
}

__global__ __launch_bounds__(1024) void scan3_kernel(int* __restrict__ rowstart,
                                                     const int* __restrict__ boff,
                                                     int* __restrict__ cursor)
{
    int i = blockIdx.x * 1024 + threadIdx.x;
    if (i < NN) {
        int r = rowstart[i] + boff[blockIdx.x];
        rowstart[i] = r;
        cursor[i] = r;
    }
}

__global__ __launch_bounds__(256) void scatter_kernel(const int* __restrict__ eidx,
                                                      int* __restrict__ cursor,
                                                      int2* __restrict__ edges_csr,
                                                      int* __restrict__ inv)
{
    int e = blockIdx.x * blockDim.x + threadIdx.x;
    int dst = eidx[e];
    int pos = atomicAdd(&cursor[dst], 1);
    edges_csr[pos] = make_int2(e, eidx[EE + e]);
    inv[e] = pos;
}

// ---------------------------------------------------------------------------
// Kernel 2: per-edge MFMA pass (R4 structure, measured 183 us).
//   4 waves x 32 edges, grid-stride over 128-edge tiles (2080 blocks).
//   Changes vs R4: eattr loads issued BEFORE the qk gather (latency hides
//   under the gather phase), cvt_pk packing everywhere pairs exist.
// ---------------------------------------------------------------------------
__global__ __launch_bounds__(256) void edge_mfma_kernel(
    const float* __restrict__ eattr, const int* __restrict__ eidx,
    const int* __restrict__ inv,
    const float* __restrict__ WEw, const float* __restrict__ WEb, const float* __restrict__ bEb,
    const float* __restrict__ WEo, const float* __restrict__ bEo, const float* __restrict__ Aw,
    const float* __restrict__ Qh, const float* __restrict__ Kh,
    float* __restrict__ Eo_out, float* __restrict__ exbuf)
{
    __shared__ unsigned short s_wew[64][68];
    __shared__ unsigned short s_web[64][68];
    __shared__ unsigned short s_weo[64][68];
    __shared__ unsigned short s_cq[4][32][68];   // qk then conn (same slots)

    int tid = threadIdx.x;
    #pragma unroll
    for (int t = 0; t < 8; ++t) {
        int idx = (t * 256 + tid) * 2;
        int r = idx >> 6, c = idx & 63;
        float2 w = *(const float2*)(WEw + idx);
        *(unsigned*)&s_wew[r][c] = cvt_pk(w.x, w.y);
        w = *(const float2*)(WEb + idx);
        *(unsigned*)&s_web[r][c] = cvt_pk(w.x, w.y);
        w = *(const float2*)(WEo + idx);
        *(unsigned*)&s_weo[r][c] = cvt_pk(w.x, w.y);
    }
    __syncthreads();

    int wid = tid >> 6, lane = tid & 63;
    int lo5 = lane & 31, hi = lane >> 5;
    int mm = lane >> 4;          // 0..3: edge-within-quad for the gather
    int cc = (lane & 15) * 4;    // feature chunk for the gather

    // Aw values matching this lane's A-fragment elements:
    // elem (ks,i) -> k = ks*16 + hi*4 + (i&3) + ((i>>2)<<3); Aw[(k&7)*8 + (k>>3)]
    float awv[32];
    #pragma unroll
    for (int ks = 0; ks < 4; ++ks)
        #pragma unroll
        for (int i = 0; i < 8; ++i) {
            int k = ks * 16 + hi * 4 + (i & 3) + ((i >> 2) << 3);
            awv[ks * 8 + i] = Aw[(k & 7) * 8 + (k >> 3)];
        }
    float bEbn0 = bEb[lo5], bEbn1 = bEb[32 + lo5];
    float bEon0 = bEo[lo5], bEon1 = bEo[32 + lo5];

    for (int tile = blockIdx.x; tile < NTILES; tile += gridDim.x) {
        int e0 = tile * 128 + wid * 32;
        int pos = inv[e0 + lo5];

        // eattr loads FIRST (latency hides under the gather phase below)
        float4 ea[8];
        {
            const float* arow = eattr + (size_t)(e0 + lo5) * 64;
            #pragma unroll
            for (int ks = 0; ks < 4; ++ks) {
                int k0 = ks * 16 + hi * 4;
                ea[2 * ks + 0] = *(const float4*)(arow + k0);
                ea[2 * ks + 1] = *(const float4*)(arow + k0 + 8);
            }
        }

        // gather qk = Qh[dst]+Kh[src] -> s_cq[wid]  (coalesced float4, bf16)
        #pragma unroll
        for (int t = 0; t < 8; ++t) {
            int m = t * 4 + mm;
            int e = e0 + m;
            int dst = eidx[e], src = eidx[EE + e];
            float4 q = *(const float4*)(Qh + (size_t)dst * 64 + cc);
            float4 k = *(const float4*)(Kh + (size_t)src * 64 + cc);
            *(uint2*)&s_cq[wid][m][cc] = make_uint2(cvt_pk(q.x + k.x, q.y + k.y),
                                                    cvt_pk(q.z + k.z, q.w + k.w));
        }

        // eattr A-fragments from the prefetched registers
        short8 af[4];
        #pragma unroll
        for (int ks = 0; ks < 4; ++ks) {
            float4 a0 = ea[2 * ks + 0], a1 = ea[2 * ks + 1];
            U8 t;
            t.u[0] = make_uint2(cvt_pk(a0.x, a0.y), cvt_pk(a0.z, a0.w));
            t.u[1] = make_uint2(cvt_pk(a1.x, a1.y), cvt_pk(a1.z, a1.w));
            af[ks] = t.v;
        }

        // Ew/Eb GEMM; epilogue reads qk and overwrites the same slot with conn
        #pragma unroll
        for (int nt = 0; nt < 2; ++nt) {
            int n = nt * 32 + lo5;
            f32x16 cEw = splat16(0.f), cEb = splat16(0.f);
            #pragma unroll
            for (int ks = 0; ks < 4; ++ks) {
                int k0 = ks * 16 + hi * 4;
                cEw = __builtin_amdgcn_mfma_f32_32x32x16_bf16(af[ks], ldsfrag(s_wew[n], k0), cEw, 0, 0, 0);
                cEb = __builtin_amdgcn_mfma_f32_32x32x16_bf16(af[ks], ldsfrag(s_web[n], k0), cEb, 0, 0, 0);
            }
            float bEbn = nt ? bEbn1 : bEbn0;
            #pragma unroll
            for (int r = 0; r < 16; ++r) {
                int m = (r & 3) + 8 * (r >> 2) + 4 * hi;
                float qk = bf2f(s_cq[wid][m][n]);
                float c1 = qk * cEw[r];
                float c2 = copysignf(sqrtf(fabsf(c1)), c1);
                s_cq[wid][m][n] = f2bf(c2 + cEb[r] + bEbn);
            }
        }

        // conn A-fragments (same-wave ds_write->ds_read, program order)
        short8 ca[4];
        #pragma unroll
        for (int ks = 0; ks < 4; ++ks) {
            int k0 = ks * 16 + hi * 4;
            ca[ks] = ldsfrag(s_cq[wid][lo5], k0);
        }

        // score on VALU: elem (ks,i) -> h = 2ks + (i>>2); shfl_xor(32) joins halves
        {
            float sc[8];
            #pragma unroll
            for (int h2 = 0; h2 < 8; ++h2) sc[h2] = 0.f;
            #pragma unroll
            for (int ks = 0; ks < 4; ++ks)
                #pragma unroll
                for (int i = 0; i < 8; ++i) {
                    float cv = bf2f((unsigned short)ca[ks][i]);
                    sc[2 * ks + (i >> 2)] = fmaf(cv, awv[ks * 8 + i], sc[2 * ks + (i >> 2)]);
                }
            #pragma unroll
            for (int h2 = 0; h2 < 8; ++h2) {
                sc[h2] += __shfl_xor(sc[h2], 32, 64);
                sc[h2] = fminf(fmaxf(sc[h2], -5.0f), 5.0f);
                sc[h2] = __expf(sc[h2]);
            }
            if (hi == 0) {   // CSR-ordered ex writes
                *(float4*)(exbuf + (size_t)pos * 8 + 0) = make_float4(sc[0], sc[1], sc[2], sc[3]);
                *(float4*)(exbuf + (size_t)pos * 8 + 4) = make_float4(sc[4], sc[5], sc[6], sc[7]);
            }
        }

        // Eo GEMM (+bias) -> output (e-ordered, coalesced 128B segments)
        #pragma unroll
        for (int nt = 0; nt < 2; ++nt) {
            int n = nt * 32 + lo5;
            f32x16 cO = splat16(nt ? bEon1 : bEon0);
            #pragma unroll
            for (int ks = 0; ks < 4; ++ks) {
                int k0 = ks * 16 + hi * 4;
                cO = __builtin_amdgcn_mfma_f32_32x32x16_bf16(ca[ks], ldsfrag(s_weo[n], k0), cO, 0, 0, 0);
            }
            #pragma unroll
            for (int r = 0; r < 16; ++r) {
                int m = (r & 3) + 8 * (r >> 2) + 4 * hi;
                Eo_out[(size_t)(e0 + m) * 64 + n] = cO[r];
            }
        }
    }
}

// ---------------------------------------------------------------------------
// Kernel 3: node aggregation (CSR). One wave per node; lane = (h,d).
//   Unroll-4: 4 independent edge iterations' loads batched in flight.
// ---------------------------------------------------------------------------
__global__ __launch_bounds__(256) void node_kernel(
    const int* __restrict__ rowstart, const int2* __restrict__ edges_csr,
    const float* __restrict__ exbuf, const float* __restrict__ Eo,
    const float* __restrict__ Vh, const float* __restrict__ BW,
    float* __restrict__ hout)
{
    int n = (blockIdx.x * blockDim.x + threadIdx.x) >> 6;
    int lane = threadIdx.x & 63;
    int h = lane >> 3, d = lane & 7;

    int beg = rowstart[n], end = rowstart[n + 1];
    float agg0 = 0.f, rv0 = 0.f, den0 = 0.f;
    float agg1 = 0.f, rv1 = 0.f, den1 = 0.f;
    int j = beg;
    for (; j + 3 < end; j += 4) {
        int2 p0 = edges_csr[j + 0];
        int2 p1 = edges_csr[j + 1];
        int2 p2 = edges_csr[j + 2];
        int2 p3 = edges_csr[j + 3];
        float x0 = exbuf[(size_t)(j + 0) * 8 + h];
        float x1 = exbuf[(size_t)(j + 1) * 8 + h];
        float x2 = exbuf[(size_t)(j + 2) * 8 + h];
        float x3 = exbuf[(size_t)(j + 3) * 8 + h];
        float v0 = Vh[(size_t)p0.y * 64 + lane];
        float o0 = Eo[(size_t)p0.x * 64 + lane];
        float v1 = Vh[(size_t)p1.y * 64 + lane];
        float o1 = Eo[(size_t)p1.x * 64 + lane];
        float v2 = Vh[(size_t)p2.y * 64 + lane];
        float o2 = Eo[(size_t)p2.x * 64 + lane];
        float v3 = Vh[(size_t)p3.y * 64 + lane];
        float o3 = Eo[(size_t)p3.x * 64 + lane];
        agg0 = fmaf(x0, v0, agg0); rv0 = fmaf(x0, o0, rv0); den0 += x0;
        agg1 = fmaf(x1, v1, agg1); rv1 = fmaf(x1, o1, rv1); den1 += x1;
        agg0 = fmaf(x2, v2, agg0); rv0 = fmaf(x2, o2, rv0); den0 += x2;
        agg1 = fmaf(x3, v3, agg1); rv1 = fmaf(x3, o3, rv1); den1 += x3;
    }
    for (; j < end; ++j) {
        int2 p0 = edges_csr[j];
        float x0 = exbuf[(size_t)j * 8 + h];
        agg0 = fmaf(x0, Vh[(size_t)p0.y * 64 + lane], agg0);
        rv0  = fmaf(x0, Eo[(size_t)p0.x * 64 + lane], rv0);
        den0 += x0;
    }
    float agg = agg0 + agg1, rv = rv0 + rv1, den = den0 + den1;
    float inv = (den > 0.f) ? (1.0f / den) : 0.f;

    float acc = agg;
    #pragma unroll
    for (int dd = 0; dd < 8; ++dd) {
        float rvd = __shfl(rv, (h << 3) + dd, 64);
        acc = fmaf(rvd, BW[dd * 64 + (h << 3) + d], acc);
    }
    hout[(size_t)n * 64 + lane] = acc * inv;
}

// ---------------------------------------------------------------------------
extern "C" void kernel_launch(void* const* d_in, const int* in_sizes, int n_in,
                              void* d_out, int out_size, void* d_ws, size_t ws_size,
                              hipStream_t stream)
{
    const float* x    = (const float*)d_in[0];
    const float* ea   = (const float*)d_in[1];
    const int*   eidx = (const int*)  d_in[2];
    const float* WQ   = (const float*)d_in[3];
    const float* WK   = (const float*)d_in[4];
    const float* WV   = (const float*)d_in[5];
    const float* WEw  = (const float*)d_in[6];
    const float* WEb  = (const float*)d_in[7];
    const float* bEb  = (const float*)d_in[8];
    const float* WEo  = (const float*)d_in[9];
    const float* bEo  = (const float*)d_in[10];
    const float* Aw   = (const float*)d_in[11];
    const float* BW   = (const float*)d_in[12];

    float* hout   = (float*)d_out;
    float* Eo_out = hout + (size_t)NN * 64;

    float* Qh    = (float*)d_ws;
    float* Kh    = Qh + (size_t)NN * 64;
    float* Vh    = Kh + (size_t)NN * 64;
    float* exbuf = Vh + (size_t)NN * 64;
    int* cnt      = (int*)(exbuf + (size_t)EE * 8);  // doubles as cursor
    int* rowstart = cnt + NN;                        // NN+2 (pad to 8B align)
    int2* edges_csr = (int2*)(rowstart + NN + 2);
    int* invp     = (int*)(edges_csr + EE);
    int* bsum     = invp + EE;
    int* boff     = bsum + 64;

    hipMemsetAsync(cnt, 0, (size_t)NN * sizeof(int), stream);

    hist_kernel<<<EE / 256, 256, 0, stream>>>(eidx, cnt);
    scan1_kernel<<<NB, 1024, 0, stream>>>(cnt, rowstart, bsum);
    scan2_kernel<<<1, 64, 0, stream>>>(bsum, boff, rowstart);
    scan3_kernel<<<NB, 1024, 0, stream>>>(rowstart, boff, cnt);
    scatter_kernel<<<EE / 256, 256, 0, stream>>>(eidx, cnt, edges_csr, invp);

    qkv_mfma_kernel<<<(NN + 127) / 128, 256, 0, stream>>>(x, WQ, WK, WV, Qh, Kh, Vh);

    edge_mfma_kernel<<<2080, 256, 0, stream>>>(ea, eidx, invp, WEw, WEb, bEb,
                                               WEo, bEo, Aw, Qh, Kh, Eo_out, exbuf);

    node_kernel<<<(NN * 64) / 256, 256, 0, stream>>>(rowstart, edges_csr,
                                                     exbuf, Eo_out, Vh, BW, hout);
}

// Round 16
// 318.740 us; speedup vs baseline: 1.1562x; 1.1562x over previous
//
#include <hip/hip_runtime.h>

#define NN 50000
#define EE 800000
#define NTILES (EE / 128)       // 6250 tiles of 128 edges (4 waves x 32)
#define NB ((NN + 1023) / 1024) // 49

typedef __attribute__((ext_vector_type(8))) short short8;
typedef __attribute__((ext_vector_type(16))) float f32x16;
typedef unsigned short ushort_t;

static __device__ __forceinline__ unsigned short f2bf(float f) {
    unsigned u = __float_as_uint(f);
    u += 0x7fffu + ((u >> 16) & 1u);
    return (unsigned short)(u >> 16);
}
// packed f32x2 -> bf16x2 (single HW instruction, RTNE)
static __device__ __forceinline__ unsigned cvt_pk(float lo, float hi) {
    unsigned r;
    asm("v_cvt_pk_bf16_f32 %0, %1, %2" : "=v"(r) : "v"(lo), "v"(hi));
    return r;
}
static __device__ __forceinline__ float bf2f(unsigned short s) {
    return __uint_as_float((unsigned)s << 16);
}
static __device__ __forceinline__ float lo_f(unsigned u) { return __uint_as_float(u << 16); }
static __device__ __forceinline__ float hi_f(unsigned u) { return __uint_as_float(u & 0xffff0000u); }
static __device__ __forceinline__ f32x16 splat16(float v) {
    f32x16 r;
    #pragma unroll
    for (int i = 0; i < 16; ++i) r[i] = v;
    return r;
}

union U8 { short8 v; uint2 u[2]; };

// read an 8-bf16 MFMA fragment: elems [0..3] at k0, [4..7] at k0+8
static __device__ __forceinline__ short8 ldsfrag(const unsigned short* rowbase, int k0) {
    U8 t;
    t.u[0] = *(const uint2*)(rowbase + k0);
    t.u[1] = *(const uint2*)(rowbase + k0 + 8);
    return t.v;
}

// ---------------------------------------------------------------------------
// Kernel 1: Qh/Kh/Vh via MFMA -> stored as BF16 (halves gather footprint:
//   tables 12.8 MB -> 6.4 MB each; one 128B line per row).
// ---------------------------------------------------------------------------
__global__ __launch_bounds__(256) void qkv_mfma_kernel(
    const float* __restrict__ x,
    const float* __restrict__ WQ, const float* __restrict__ WK, const float* __restrict__ WV,
    ushort_t* __restrict__ Qb, ushort_t* __restrict__ Kb, ushort_t* __restrict__ Vb)
{
    __shared__ unsigned short s_wq[64][68];
    __shared__ unsigned short s_wk[64][68];
    __shared__ unsigned short s_wv[64][68];

    int tid = threadIdx.x;
    #pragma unroll
    for (int t = 0; t < 8; ++t) {
        int idx = (t * 256 + tid) * 2;
        int r = idx >> 6, c = idx & 63;
        float2 w = *(const float2*)(WQ + idx);
        *(unsigned*)&s_wq[r][c] = cvt_pk(w.x, w.y);
        w = *(const float2*)(WK + idx);
        *(unsigned*)&s_wk[r][c] = cvt_pk(w.x, w.y);
        w = *(const float2*)(WV + idx);
        *(unsigned*)&s_wv[r][c] = cvt_pk(w.x, w.y);
    }
    __syncthreads();

    int wid = tid >> 6, lane = tid & 63;
    int m0 = blockIdx.x * 128 + wid * 32;
    int lo5 = lane & 31, hi = lane >> 5;

    int rowi = m0 + lo5;
    const float* arow = x + (size_t)(rowi < NN ? rowi : NN - 1) * 64;
    short8 af[4];
    #pragma unroll
    for (int ks = 0; ks < 4; ++ks) {
        int k0 = ks * 16 + hi * 4;
        float4 a0 = *(const float4*)(arow + k0);
        float4 a1 = *(const float4*)(arow + k0 + 8);
        U8 t;
        t.u[0] = make_uint2(cvt_pk(a0.x, a0.y), cvt_pk(a0.z, a0.w));
        t.u[1] = make_uint2(cvt_pk(a1.x, a1.y), cvt_pk(a1.z, a1.w));
        af[ks] = t.v;
    }

    #pragma unroll
    for (int nt = 0; nt < 2; ++nt) {
        int n = nt * 32 + lo5;
        f32x16 cQ = splat16(0.f), cK = splat16(0.f), cV = splat16(0.f);
        #pragma unroll
        for (int ks = 0; ks < 4; ++ks) {
            int k0 = ks * 16 + hi * 4;
            cQ = __builtin_amdgcn_mfma_f32_32x32x16_bf16(af[ks], ldsfrag(s_wq[n], k0), cQ, 0, 0, 0);
            cK = __builtin_amdgcn_mfma_f32_32x32x16_bf16(af[ks], ldsfrag(s_wk[n], k0), cK, 0, 0, 0);
            cV = __builtin_amdgcn_mfma_f32_32x32x16_bf16(af[ks], ldsfrag(s_wv[n], k0), cV, 0, 0, 0);
        }
        #pragma unroll
        for (int r = 0; r < 16; ++r) {
            int m = (r & 3) + 8 * (r >> 2) + 4 * hi;
            int gm = m0 + m;
            if (gm < NN) {
                Qb[(size_t)gm * 64 + n] = (ushort_t)cvt_pk(cQ[r], cQ[r]);
                Kb[(size_t)gm * 64 + n] = (ushort_t)cvt_pk(cK[r], cK[r]);
                Vb[(size_t)gm * 64 + n] = (ushort_t)cvt_pk(cV[r], cV[r]);
            }
        }
    }
}

// ---------------------------------------------------------------------------
// CSR build: histogram -> hierarchical scan -> scatter (combined int2 + inv)
// ---------------------------------------------------------------------------
__global__ __launch_bounds__(256) void hist_kernel(const int* __restrict__ eidx,
                                                   int* __restrict__ cnt)
{
    int e = blockIdx.x * blockDim.x + threadIdx.x;
    atomicAdd(&cnt[eidx[e]], 1);
}

__global__ __launch_bounds__(1024) void scan1_kernel(const int* __restrict__ cnt,
                                                     int* __restrict__ rowstart,
                                                     int* __restrict__ bsum)
{
    __shared__ int buf[1024];
    int tid = threadIdx.x;
    int i = blockIdx.x * 1024 + tid;
    int v = (i < NN) ? cnt[i] : 0;
    buf[tid] = v;
    __syncthreads();
    for (int off = 1; off < 1024; off <<= 1) {
        int t = (tid >= off) ? buf[tid - off] : 0;
        __syncthreads();
        buf[tid] += t;
        __syncthreads();
    }
    if (i < NN) rowstart[i] = buf[tid] - v;
    if (tid == 1023) bsum[blockIdx.x] = buf[1023];
}

__global__ __launch_bounds__(64) void scan2_kernel(const int* __restrict__ bsum,
                                                   int* __restrict__ boff,
                                                   int* __restrict__ rowstart)
{
    int lane = threadIdx.x;
    int v = (lane < NB) ? bsum[lane] : 0;
    int s = v;
    #pragma unroll
    for (int off = 1; off < 64; off <<= 1) {
        int t = __shfl_up(s, off, 64);
        if (lane >= off) s += t;
    }
    if (lane < NB) boff[lane] = s - v;
    if (lane == 63) rowstart[NN] = s;
}

__global__ __launch_bounds__(1024) void scan3_kernel(int* __restrict__ rowstart,
                                                     const int* __restrict__ boff,
                                                     int* __restrict__ cursor)
{
    int i = blockIdx.x * 1024 + threadIdx.x;
    if (i < NN) {
        int r = rowstart[i] + boff[blockIdx.x];
        rowstart[i] = r;
        cursor[i] = r;
    }
}

__global__ __launch_bounds__(256) void scatter_kernel(const int* __restrict__ eidx,
                                                      int* __restrict__ cursor,
                                                      int2* __restrict__ edges_csr,
                                                      int* __restrict__ inv)
{
    int e = blockIdx.x * blockDim.x + threadIdx.x;
    int dst = eidx[e];
    int pos = atomicAdd(&cursor[dst], 1);
    edges_csr[pos] = make_int2(e, eidx[EE + e]);
    inv[e] = pos;
}

// ---------------------------------------------------------------------------
// Kernel 2: per-edge MFMA pass (R4 structure — measured best).
//   4 waves x 32 edges, grid-stride over 128-edge tiles (2080 blocks).
//   bf16 Q/K tables: gather is 8B/lane-group-element, 128B/row (1 line).
// ---------------------------------------------------------------------------
__global__ __launch_bounds__(256) void edge_mfma_kernel(
    const float* __restrict__ eattr, const int* __restrict__ eidx,
    const int* __restrict__ inv,
    const float* __restrict__ WEw, const float* __restrict__ WEb, const float* __restrict__ bEb,
    const float* __restrict__ WEo, const float* __restrict__ bEo, const float* __restrict__ Aw,
    const ushort_t* __restrict__ Qb, const ushort_t* __restrict__ Kb,
    float* __restrict__ Eo_out, float* __restrict__ exbuf)
{
    __shared__ unsigned short s_wew[64][68];
    __shared__ unsigned short s_web[64][68];
    __shared__ unsigned short s_weo[64][68];
    __shared__ unsigned short s_cq[4][32][68];   // qk then conn (same slots)

    int tid = threadIdx.x;
    #pragma unroll
    for (int t = 0; t < 8; ++t) {
        int idx = (t * 256 + tid) * 2;
        int r = idx >> 6, c = idx & 63;
        float2 w = *(const float2*)(WEw + idx);
        *(unsigned*)&s_wew[r][c] = cvt_pk(w.x, w.y);
        w = *(const float2*)(WEb + idx);
        *(unsigned*)&s_web[r][c] = cvt_pk(w.x, w.y);
        w = *(const float2*)(WEo + idx);
        *(unsigned*)&s_weo[r][c] = cvt_pk(w.x, w.y);
    }
    __syncthreads();

    int wid = tid >> 6, lane = tid & 63;
    int lo5 = lane & 31, hi = lane >> 5;
    int mm = lane >> 4;          // 0..3: edge-within-quad for the gather
    int cc = (lane & 15) * 4;    // feature chunk for the gather

    // Aw values matching this lane's A-fragment elements:
    // elem (ks,i) -> k = ks*16 + hi*4 + (i&3) + ((i>>2)<<3); Aw[(k&7)*8 + (k>>3)]
    float awv[32];
    #pragma unroll
    for (int ks = 0; ks < 4; ++ks)
        #pragma unroll
        for (int i = 0; i < 8; ++i) {
            int k = ks * 16 + hi * 4 + (i & 3) + ((i >> 2) << 3);
            awv[ks * 8 + i] = Aw[(k & 7) * 8 + (k >> 3)];
        }
    float bEbn0 = bEb[lo5], bEbn1 = bEb[32 + lo5];
    float bEon0 = bEo[lo5], bEon1 = bEo[32 + lo5];

    for (int tile = blockIdx.x; tile < NTILES; tile += gridDim.x) {
        int e0 = tile * 128 + wid * 32;
        int pos = inv[e0 + lo5];

        // gather qk = Qb[dst]+Kb[src] -> s_cq[wid]  (8B loads, 128B/row, bf16)
        #pragma unroll
        for (int t = 0; t < 8; ++t) {
            int m = t * 4 + mm;
            int e = e0 + m;
            int dst = eidx[e], src = eidx[EE + e];
            uint2 q = *(const uint2*)(Qb + (size_t)dst * 64 + cc);
            uint2 k = *(const uint2*)(Kb + (size_t)src * 64 + cc);
            float s0 = lo_f(q.x) + lo_f(k.x);
            float s1 = hi_f(q.x) + hi_f(k.x);
            float s2 = lo_f(q.y) + lo_f(k.y);
            float s3 = hi_f(q.y) + hi_f(k.y);
            *(uint2*)&s_cq[wid][m][cc] = make_uint2(cvt_pk(s0, s1), cvt_pk(s2, s3));
        }

        // eattr A-fragments
        short8 af[4];
        {
            const float* arow = eattr + (size_t)(e0 + lo5) * 64;
            #pragma unroll
            for (int ks = 0; ks < 4; ++ks) {
                int k0 = ks * 16 + hi * 4;
                float4 a0 = *(const float4*)(arow + k0);
                float4 a1 = *(const float4*)(arow + k0 + 8);
                U8 t;
                t.u[0] = make_uint2(cvt_pk(a0.x, a0.y), cvt_pk(a0.z, a0.w));
                t.u[1] = make_uint2(cvt_pk(a1.x, a1.y), cvt_pk(a1.z, a1.w));
                af[ks] = t.v;
            }
        }

        // Ew/Eb GEMM; epilogue reads qk and overwrites the same slot with conn
        #pragma unroll
        for (int nt = 0; nt < 2; ++nt) {
            int n = nt * 32 + lo5;
            f32x16 cEw = splat16(0.f), cEb = splat16(0.f);
            #pragma unroll
            for (int ks = 0; ks < 4; ++ks) {
                int k0 = ks * 16 + hi * 4;
                cEw = __builtin_amdgcn_mfma_f32_32x32x16_bf16(af[ks], ldsfrag(s_wew[n], k0), cEw, 0, 0, 0);
                cEb = __builtin_amdgcn_mfma_f32_32x32x16_bf16(af[ks], ldsfrag(s_web[n], k0), cEb, 0, 0, 0);
            }
            float bEbn = nt ? bEbn1 : bEbn0;
            #pragma unroll
            for (int r = 0; r < 16; ++r) {
                int m = (r & 3) + 8 * (r >> 2) + 4 * hi;
                float qk = bf2f(s_cq[wid][m][n]);
                float c1 = qk * cEw[r];
                float c2 = copysignf(sqrtf(fabsf(c1)), c1);
                s_cq[wid][m][n] = f2bf(c2 + cEb[r] + bEbn);
            }
        }

        // conn A-fragments (same-wave ds_write->ds_read, program order)
        short8 ca[4];
        #pragma unroll
        for (int ks = 0; ks < 4; ++ks) {
            int k0 = ks * 16 + hi * 4;
            ca[ks] = ldsfrag(s_cq[wid][lo5], k0);
        }

        // score on VALU: elem (ks,i) -> h = 2ks + (i>>2); shfl_xor(32) joins halves
        {
            float sc[8];
            #pragma unroll
            for (int h2 = 0; h2 < 8; ++h2) sc[h2] = 0.f;
            #pragma unroll
            for (int ks = 0; ks < 4; ++ks)
                #pragma unroll
                for (int i = 0; i < 8; ++i) {
                    float cv = bf2f((unsigned short)ca[ks][i]);
                    sc[2 * ks + (i >> 2)] = fmaf(cv, awv[ks * 8 + i], sc[2 * ks + (i >> 2)]);
                }
            #pragma unroll
            for (int h2 = 0; h2 < 8; ++h2) {
                sc[h2] += __shfl_xor(sc[h2], 32, 64);
                sc[h2] = fminf(fmaxf(sc[h2], -5.0f), 5.0f);
                sc[h2] = __expf(sc[h2]);
            }
            if (hi == 0) {   // CSR-ordered ex writes
                *(float4*)(exbuf + (size_t)pos * 8 + 0) = make_float4(sc[0], sc[1], sc[2], sc[3]);
                *(float4*)(exbuf + (size_t)pos * 8 + 4) = make_float4(sc[4], sc[5], sc[6], sc[7]);
            }
        }

        // Eo GEMM (+bias) -> output (e-ordered, coalesced 128B segments)
        #pragma unroll
        for (int nt = 0; nt < 2; ++nt) {
            int n = nt * 32 + lo5;
            f32x16 cO = splat16(nt ? bEon1 : bEon0);
            #pragma unroll
            for (int ks = 0; ks < 4; ++ks) {
                int k0 = ks * 16 + hi * 4;
                cO = __builtin_amdgcn_mfma_f32_32x32x16_bf16(ca[ks], ldsfrag(s_weo[n], k0), cO, 0, 0, 0);
            }
            #pragma unroll
            for (int r = 0; r < 16; ++r) {
                int m = (r & 3) + 8 * (r >> 2) + 4 * hi;
                Eo_out[(size_t)(e0 + m) * 64 + n] = cO[r];
            }
        }
    }
}

// ---------------------------------------------------------------------------
// Kernel 3: node aggregation (CSR). One wave per node; lane = (h,d).
//   Unroll-4 with batched loads; Vh read as bf16 (1 line per row).
// ---------------------------------------------------------------------------
__global__ __launch_bounds__(256) void node_kernel(
    const int* __restrict__ rowstart, const int2* __restrict__ edges_csr,
    const float* __restrict__ exbuf, const float* __restrict__ Eo,
    const ushort_t* __restrict__ Vb, const float* __restrict__ BW,
    float* __restrict__ hout)
{
    int n = (blockIdx.x * blockDim.x + threadIdx.x) >> 6;
    int lane = threadIdx.x & 63;
    int h = lane >> 3, d = lane & 7;

    int beg = rowstart[n], end = rowstart[n + 1];
    float agg0 = 0.f, rv0 = 0.f, den0 = 0.f;
    float agg1 = 0.f, rv1 = 0.f, den1 = 0.f;
    int j = beg;
    for (; j + 3 < end; j += 4) {
        int2 p0 = edges_csr[j + 0];
        int2 p1 = edges_csr[j + 1];
        int2 p2 = edges_csr[j + 2];
        int2 p3 = edges_csr[j + 3];
        float x0 = exbuf[(size_t)(j + 0) * 8 + h];
        float x1 = exbuf[(size_t)(j + 1) * 8 + h];
        float x2 = exbuf[(size_t)(j + 2) * 8 + h];
        float x3 = exbuf[(size_t)(j + 3) * 8 + h];
        float v0 = bf2f(Vb[(size_t)p0.y * 64 + lane]);
        float o0 = Eo[(size_t)p0.x * 64 + lane];
        float v1 = bf2f(Vb[(size_t)p1.y * 64 + lane]);
        float o1 = Eo[(size_t)p1.x * 64 + lane];
        float v2 = bf2f(Vb[(size_t)p2.y * 64 + lane]);
        float o2 = Eo[(size_t)p2.x * 64 + lane];
        float v3 = bf2f(Vb[(size_t)p3.y * 64 + lane]);
        float o3 = Eo[(size_t)p3.x * 64 + lane];
        agg0 = fmaf(x0, v0, agg0); rv0 = fmaf(x0, o0, rv0); den0 += x0;
        agg1 = fmaf(x1, v1, agg1); rv1 = fmaf(x1, o1, rv1); den1 += x1;
        agg0 = fmaf(x2, v2, agg0); rv0 = fmaf(x2, o2, rv0); den0 += x2;
        agg1 = fmaf(x3, v3, agg1); rv1 = fmaf(x3, o3, rv1); den1 += x3;
    }
    for (; j < end; ++j) {
        int2 p0 = edges_csr[j];
        float x0 = exbuf[(size_t)j * 8 + h];
        agg0 = fmaf(x0, bf2f(Vb[(size_t)p0.y * 64 + lane]), agg0);
        rv0  = fmaf(x0, Eo[(size_t)p0.x * 64 + lane], rv0);
        den0 += x0;
    }
    float agg = agg0 + agg1, rv = rv0 + rv1, den = den0 + den1;
    float inv = (den > 0.f) ? (1.0f / den) : 0.f;

    float acc = agg;
    #pragma unroll
    for (int dd = 0; dd < 8; ++dd) {
        float rvd = __shfl(rv, (h << 3) + dd, 64);
        acc = fmaf(rvd, BW[dd * 64 + (h << 3) + d], acc);
    }
    hout[(size_t)n * 64 + lane] = acc * inv;
}

// ---------------------------------------------------------------------------
extern "C" void kernel_launch(void* const* d_in, const int* in_sizes, int n_in,
                              void* d_out, int out_size, void* d_ws, size_t ws_size,
                              hipStream_t stream)
{
    const float* x    = (const float*)d_in[0];
    const float* ea   = (const float*)d_in[1];
    const int*   eidx = (const int*)  d_in[2];
    const float* WQ   = (const float*)d_in[3];
    const float* WK   = (const float*)d_in[4];
    const float* WV   = (const float*)d_in[5];
    const float* WEw  = (const float*)d_in[6];
    const float* WEb  = (const float*)d_in[7];
    const float* bEb  = (const float*)d_in[8];
    const float* WEo  = (const float*)d_in[9];
    const float* bEo  = (const float*)d_in[10];
    const float* Aw   = (const float*)d_in[11];
    const float* BW   = (const float*)d_in[12];

    float* hout   = (float*)d_out;
    float* Eo_out = hout + (size_t)NN * 64;

    // workspace: Qb | Kb | Vb (bf16) | exbuf | cnt | rowstart | edges_csr | inv | bsum | boff
    ushort_t* Qb = (ushort_t*)d_ws;
    ushort_t* Kb = Qb + (size_t)NN * 64;
    ushort_t* Vb = Kb + (size_t)NN * 64;
    float* exbuf = (float*)(Vb + (size_t)NN * 64);
    int* cnt      = (int*)(exbuf + (size_t)EE * 8);  // doubles as cursor
    int* rowstart = cnt + NN;                        // NN+2 (pad to 8B align)
    int2* edges_csr = (int2*)(rowstart + NN + 2);
    int* invp     = (int*)(edges_csr + EE);
    int* bsum     = invp + EE;
    int* boff     = bsum + 64;

    hipMemsetAsync(cnt, 0, (size_t)NN * sizeof(int), stream);

    hist_kernel<<<EE / 256, 256, 0, stream>>>(eidx, cnt);
    scan1_kernel<<<NB, 1024, 0, stream>>>(cnt, rowstart, bsum);
    scan2_kernel<<<1, 64, 0, stream>>>(bsum, boff, rowstart);
    scan3_kernel<<<NB, 1024, 0, stream>>>(rowstart, boff, cnt);
    scatter_kernel<<<EE / 256, 256, 0, stream>>>(eidx, cnt, edges_csr, invp);

    qkv_mfma_kernel<<<(NN + 127) / 128, 256, 0, stream>>>(x, WQ, WK, WV, Qb, Kb, Vb);

    edge_mfma_kernel<<<2080, 256, 0, stream>>>(ea, eidx, invp, WEw, WEb, bEb,
                                               WEo, bEo, Aw, Qb, Kb, Eo_out, exbuf);

    node_kernel<<<(NN * 64) / 256, 256, 0, stream>>>(rowstart, edges_csr,
                                                     exbuf, Eo_out, Vb, BW, hout);
}